// Round 3
// baseline (277.653 us; speedup 1.0000x reference)
//
#include <hip/hip_runtime.h>
#include <stdint.h>

#define BATCH 32
#define CIN   64
#define HH    112
#define WW    112
#define COUT_ 64

// padded NHWC repack geometry: [b][hp 0..113][col 0..112][72B]
//   col = w+1 (col 0 = left zero pad); right pad (w=112) = next row's col 0.
#define ROWB  8136            // 113 * 72
#define IMGB  (114 * ROWB)    // 927,504
#define XPAD_OFF 40960
#define WS_REQ (XPAD_OFF + (size_t)BATCH * IMGB)   // 29,721,088 B

typedef int v4i __attribute__((ext_vector_type(4)));

__device__ inline void async_copy16(const void* g, void* l) {
    __builtin_amdgcn_global_load_lds(
        (const __attribute__((address_space(1))) uint8_t*)g,
        (__attribute__((address_space(3))) uint8_t*)l, 16, 0, 0);
}

// ---- Kernel 0: weights int32 -> int8, [co][ci][kh][kw] -> [co][kh][kw][ci] ----
__global__ void wtrans_kernel(const int* __restrict__ wq, int8_t* __restrict__ wt) {
    int idx = blockIdx.x * 256 + threadIdx.x;   // 0 .. 36863, exact
    int ci   = idx & 63;
    int khkw = (idx >> 6) % 9;
    int co   = idx / 576;
    wt[idx] = (int8_t)wq[co * 576 + ci * 9 + khkw];
}

// ---- Pass 1: x int32 NCHW -> int8 padded NHWC (x_pad) ----
// One block per (b, h) row. Streaming: 28.7 KB fetch + 8.3 KB write per block.
__global__ void repack_kernel(const int* __restrict__ x, int8_t* __restrict__ xp) {
    const int tid = threadIdx.x;
    const int b   = blockIdx.x / HH;
    const int h   = blockIdx.x % HH;
    int8_t* rowb = xp + (size_t)(b * 114 + h + 1) * ROWB;

    // 448 jobs = 16 ci4-groups x 28 col-groups
    #pragma unroll
    for (int it = 0; it < 2; ++it) {
        int job = tid + it * 256;
        if (job < 448) {
            int ci4 = job & 15;
            int cg  = job >> 4;
            const v4i* gp = (const v4i*)
                (x + ((size_t)(b * CIN + ci4 * 4) * HH + h) * WW + cg * 4);
            v4i q0 = gp[0];
            v4i q1 = gp[3136];          // +1 ci plane (112*112/4 int4s)
            v4i q2 = gp[2 * 3136];
            v4i q3 = gp[3 * 3136];
            #pragma unroll
            for (int j = 0; j < 4; ++j) {
                uint32_t lo01 = __builtin_amdgcn_perm((uint32_t)q1[j], (uint32_t)q0[j], 0x0C0C0400u);
                uint32_t lo23 = __builtin_amdgcn_perm((uint32_t)q3[j], (uint32_t)q2[j], 0x04000C0Cu);
                *(uint32_t*)&rowb[(cg * 4 + 1 + j) * 72 + ci4 * 4] = lo01 | lo23;
            }
        }
    }
    // zero: left pad column (72B) and the 8B tail of each data pixel
    if (tid < 18) *(uint32_t*)&rowb[tid * 4] = 0u;
    if (tid >= 32 && tid < 144) {
        int wp = tid - 31;                     // 1..112
        *(uint64_t*)&rowb[wp * 72 + 64] = 0ull;
    }
    // zero pad rows hp=0 and hp=113
    if (h == 0) {
        int8_t* zr = xp + (size_t)(b * 114 + 0) * ROWB;
        for (int i = tid; i < ROWB / 4; i += 256) *(uint32_t*)&zr[i * 4] = 0u;
    }
    if (h == HH - 1) {
        int8_t* zr = xp + (size_t)(b * 114 + 113) * ROWB;
        for (int i = tid; i < ROWB / 4; i += 256) *(uint32_t*)&zr[i * 4] = 0u;
    }
}

// ---- Pass 2: conv. Stage 4 padded rows via global_load_lds, MFMA, dequant ----
__launch_bounds__(256, 5)
__global__ void conv_kernel(const int8_t* __restrict__ xp,
                            const int8_t* __restrict__ wt,
                            const float*  __restrict__ wscale,
                            const float*  __restrict__ ascale,
                            const float*  __restrict__ bias,
                            float*        __restrict__ out) {
    __shared__ int8_t xs[4 * ROWB + 72];   // 32,616 B -> 5 blocks/CU

    const int tid  = threadIdx.x;
    const int lane = tid & 63;
    const int wave = tid >> 6;
    const int bt   = blockIdx.x;
    const int b    = bt / 56;
    const int h0   = (bt % 56) * 2;        // staged padded rows hp = h0 .. h0+3

    // contiguous async copy: 4*8136 = 32,544 B = 2034 x 16B chunks
    const int8_t* gsrc = xp + (size_t)(b * 114 + h0) * ROWB;
    #pragma unroll
    for (int it = 0; it < 8; ++it) {
        int chunk = it * 256 + tid;
        if (chunk < 2034)
            async_copy16(gsrc + (size_t)chunk * 16, xs + (it * 256 + wave * 64) * 16);
    }
    // zero the 72B tail (serves as "row 4, col 0" for row-3 col-113 reads)
    if (tid < 18) *(uint32_t*)&xs[4 * ROWB + tid * 4] = 0u;

    const int ln15 = lane & 15;
    const int quad = lane >> 4;
    const int r    = wave >> 1;            // output row within tile (0/1)
    const int coh  = wave & 1;             // cout half
    const int cobase = coh * 32;

    v4i acc[2][7];
    #pragma unroll
    for (int mt = 0; mt < 2; ++mt)
        #pragma unroll
        for (int nt = 0; nt < 7; ++nt)
            acc[mt][nt] = (v4i){0, 0, 0, 0};

    // A rows: wt[co][k], k = (kh*3+kw)*64 + ci ; frag = 8B at k = kc*32+quad*8
    const long* w64a = (const long*)(wt + (size_t)(cobase + ln15) * 576);
    const long* w64b = (const long*)(wt + (size_t)(cobase + 16 + ln15) * 576);

    __syncthreads();   // drains vmcnt (global_load_lds) + lgkm

    #pragma unroll
    for (int kc = 0; kc < 18; ++kc) {
        const int khkw = kc >> 1;
        const int kh   = khkw / 3;
        const int kw   = khkw % 3;
        const int half = kc & 1;
        long a0 = w64a[kc * 4 + quad];
        long a1 = w64b[kc * 4 + quad];
        const int rb = (kh + r) * ROWB + half * 32 + quad * 8;
        #pragma unroll
        for (int nt = 0; nt < 7; ++nt) {
            int col = nt * 16 + ln15 + kw;          // 0..113; 113 wraps to next row's zero col
            long bfrag = *(const long*)&xs[rb + col * 72];
            acc[0][nt] = __builtin_amdgcn_mfma_i32_16x16x32_i8(a0, bfrag, acc[0][nt], 0, 0, 0);
            acc[1][nt] = __builtin_amdgcn_mfma_i32_16x16x32_i8(a1, bfrag, acc[1][nt], 0, 0, 0);
        }
    }

    // fused dequant + bias epilogue
    const float s = ascale[0] * wscale[0];
    const int h = h0 + r;
    #pragma unroll
    for (int mt = 0; mt < 2; ++mt) {
        #pragma unroll
        for (int reg = 0; reg < 4; ++reg) {
            int co = cobase + mt * 16 + quad * 4 + reg;   // C/D: row = quad*4+reg
            float bv = bias[co];
            float* op = out + ((size_t)(b * COUT_ + co) * HH + h) * WW;
            #pragma unroll
            for (int nt = 0; nt < 7; ++nt) {
                int wp = nt * 16 + ln15;                  // C/D: col = lane&15
                op[wp] = (float)acc[mt][nt][reg] * s + bv;
            }
        }
    }
}

// ---- Fallback (R2 path, verified passing): single-pass from int32 x ----
__launch_bounds__(256, 2)
__global__ void conv_fb(const int* __restrict__ x,
                        const int8_t* __restrict__ wt,
                        const float*  __restrict__ wscale,
                        const float*  __restrict__ ascale,
                        const float*  __restrict__ bias,
                        float*        __restrict__ out) {
    __shared__ int8_t xs[4 * 114 * 72];

    const int tid = threadIdx.x;
    const int bt  = blockIdx.x;
    const int b   = bt / 56;
    const int h0  = (bt % 56) * 2;

    #pragma unroll
    for (int it = 0; it < 7; ++it) {
        int job = tid + it * 256;
        int ci4 = job & 15;
        int cg  = (job >> 4) % 28;
        int row = job / 448;
        int hh  = h0 - 1 + row;
        v4i q0 = {0,0,0,0}, q1 = {0,0,0,0}, q2 = {0,0,0,0}, q3 = {0,0,0,0};
        if (hh >= 0 && hh < HH) {
            const v4i* gp = (const v4i*)
                (x + ((size_t)(b * CIN + ci4 * 4) * HH + hh) * WW + cg * 4);
            q0 = gp[0]; q1 = gp[3136]; q2 = gp[2 * 3136]; q3 = gp[3 * 3136];
        }
        #pragma unroll
        for (int j = 0; j < 4; ++j) {
            uint32_t lo01 = __builtin_amdgcn_perm((uint32_t)q1[j], (uint32_t)q0[j], 0x0C0C0400u);
            uint32_t lo23 = __builtin_amdgcn_perm((uint32_t)q3[j], (uint32_t)q2[j], 0x04000C0Cu);
            *(uint32_t*)&xs[(row * 114 + cg * 4 + 1 + j) * 72 + ci4 * 4] = lo01 | lo23;
        }
    }
    if (tid < 128) {
        int ci4 = tid & 15;
        int col = ((tid >> 4) & 1) ? 113 : 0;
        int row = tid >> 5;
        *(uint32_t*)&xs[(row * 114 + col) * 72 + ci4 * 4] = 0u;
    }
    __syncthreads();

    const int lane = tid & 63;
    const int wave = tid >> 6;
    const int ln15 = lane & 15;
    const int quad = lane >> 4;
    const int r    = wave >> 1;
    const int coh  = wave & 1;
    const int cobase = coh * 32;

    v4i acc[2][7];
    #pragma unroll
    for (int mt = 0; mt < 2; ++mt)
        #pragma unroll
        for (int nt = 0; nt < 7; ++nt)
            acc[mt][nt] = (v4i){0, 0, 0, 0};

    const long* w64a = (const long*)(wt + (size_t)(cobase + ln15) * 576);
    const long* w64b = (const long*)(wt + (size_t)(cobase + 16 + ln15) * 576);

    #pragma unroll
    for (int kc = 0; kc < 18; ++kc) {
        const int khkw = kc >> 1;
        const int kh   = khkw / 3;
        const int kw   = khkw % 3;
        const int half = kc & 1;
        long a0 = w64a[kc * 4 + quad];
        long a1 = w64b[kc * 4 + quad];
        const int rowb  = (kh + r) * 114;
        const int cioff = half * 32 + quad * 8;
        #pragma unroll
        for (int nt = 0; nt < 7; ++nt) {
            int col = nt * 16 + ln15 + kw;
            long bfrag = *(const long*)&xs[(rowb + col) * 72 + cioff];
            acc[0][nt] = __builtin_amdgcn_mfma_i32_16x16x32_i8(a0, bfrag, acc[0][nt], 0, 0, 0);
            acc[1][nt] = __builtin_amdgcn_mfma_i32_16x16x32_i8(a1, bfrag, acc[1][nt], 0, 0, 0);
        }
    }

    const float s = ascale[0] * wscale[0];
    const int h = h0 + r;
    #pragma unroll
    for (int mt = 0; mt < 2; ++mt) {
        #pragma unroll
        for (int reg = 0; reg < 4; ++reg) {
            int co = cobase + mt * 16 + quad * 4 + reg;
            float bv = bias[co];
            float* op = out + ((size_t)(b * COUT_ + co) * HH + h) * WW;
            #pragma unroll
            for (int nt = 0; nt < 7; ++nt) {
                int wp = nt * 16 + ln15;
                op[wp] = (float)acc[mt][nt][reg] * s + bv;
            }
        }
    }
}

extern "C" void kernel_launch(void* const* d_in, const int* in_sizes, int n_in,
                              void* d_out, int out_size, void* d_ws, size_t ws_size,
                              hipStream_t stream) {
    const int*    xq     = (const int*)d_in[0];
    const int*    wq     = (const int*)d_in[1];
    const float*  wscale = (const float*)d_in[2];
    const float*  ascale = (const float*)d_in[3];
    const float*  bias   = (const float*)d_in[4];
    int8_t* wt  = (int8_t*)d_ws;
    float*  out = (float*)d_out;

    wtrans_kernel<<<144, 256, 0, stream>>>(wq, wt);
    if (ws_size >= WS_REQ) {
        int8_t* xp = (int8_t*)d_ws + XPAD_OFF;
        repack_kernel<<<BATCH * HH, 256, 0, stream>>>(xq, xp);
        conv_kernel<<<BATCH * 56, 256, 0, stream>>>(xp, wt, wscale, ascale, bias, out);
    } else {
        conv_fb<<<BATCH * 56, 256, 0, stream>>>(xq, wt, wscale, ascale, bias, out);
    }
}

// Round 4
// 220.120 us; speedup vs baseline: 1.2614x; 1.2614x over previous
//
#include <hip/hip_runtime.h>
#include <stdint.h>

#define BATCH 32
#define CIN   64
#define HH    112
#define WW    112
#define COUT_ 64

typedef int v4i __attribute__((ext_vector_type(4)));

// Kernel 0: weights int32 -> int8, [co][ci][kh][kw] -> [co][kh][kw][ci] so
// A-fragments (16 consecutive k = contiguous ci at a fixed tap) are 8B loads.
__global__ void wtrans_kernel(const int* __restrict__ wq, int8_t* __restrict__ wt) {
    int idx = blockIdx.x * 256 + threadIdx.x;   // 0 .. 36863, exact
    int ci   = idx & 63;
    int khkw = (idx >> 6) % 9;
    int co   = idx / 576;
    wt[idx] = (int8_t)wq[co * 576 + ci * 9 + khkw];
}

// Main conv kernel. Block = 256 threads (4 waves), one (b, 2-row) tile.
// Staging identical to the verified R2 kernel. New epilogue: acc -> LDS
// (fp32, pitch 116 dwords = 2-way-only bank aliasing) -> coalesced float4
// stores (full 448B row runs, full cache lines).
__launch_bounds__(256, 2)
__global__ void conv_kernel(const int* __restrict__ x,       // int32-materialized int8
                            const int8_t* __restrict__ wt,
                            const float*  __restrict__ wscale,
                            const float*  __restrict__ ascale,
                            const float*  __restrict__ bias,
                            float*        __restrict__ out) {
    __shared__ __align__(16) int8_t xs[4 * 114 * 72];   // 32,832 B; reused as fp32 buf

    const int tid = threadIdx.x;
    const int bt  = blockIdx.x;
    const int b   = bt / 56;
    const int h0  = (bt % 56) * 2;

    // ---- stage x tile: int32 -> int8, transpose w<->ci via v_perm ----
    #pragma unroll
    for (int it = 0; it < 7; ++it) {
        int job = tid + it * 256;
        int ci4 = job & 15;            // ci = ci4*4
        int cg  = (job >> 4) % 28;     // w = cg*4
        int row = job / 448;           // 0..3
        int hh  = h0 - 1 + row;
        v4i q0 = {0,0,0,0}, q1 = {0,0,0,0}, q2 = {0,0,0,0}, q3 = {0,0,0,0};
        if (hh >= 0 && hh < HH) {
            const v4i* gp = (const v4i*)
                (x + ((size_t)(b * CIN + ci4 * 4) * HH + hh) * WW + cg * 4);
            q0 = gp[0];
            q1 = gp[3136];          // +1 ci plane (112*112/4 int4s)
            q2 = gp[2 * 3136];
            q3 = gp[3 * 3136];
        }
        #pragma unroll
        for (int j = 0; j < 4; ++j) {
            uint32_t lo01 = __builtin_amdgcn_perm((uint32_t)q1[j], (uint32_t)q0[j], 0x0C0C0400u);
            uint32_t lo23 = __builtin_amdgcn_perm((uint32_t)q3[j], (uint32_t)q2[j], 0x04000C0Cu);
            *(uint32_t*)&xs[(row * 114 + cg * 4 + 1 + j) * 72 + ci4 * 4] = lo01 | lo23;
        }
    }
    if (tid < 128) {   // zero pad columns (input cols -1 and 112)
        int ci4 = tid & 15;
        int col = ((tid >> 4) & 1) ? 113 : 0;
        int row = tid >> 5;
        *(uint32_t*)&xs[(row * 114 + col) * 72 + ci4 * 4] = 0u;
    }
    __syncthreads();

    // ---- MFMA main loop (verified layout) ----
    const int lane = tid & 63;
    const int wave = tid >> 6;
    const int ln15 = lane & 15;
    const int quad = lane >> 4;
    const int r    = wave >> 1;        // output row within tile (0/1)
    const int coh  = wave & 1;         // cout half
    const int cobase = coh * 32;

    v4i acc[2][7];
    #pragma unroll
    for (int mt = 0; mt < 2; ++mt)
        #pragma unroll
        for (int nt = 0; nt < 7; ++nt)
            acc[mt][nt] = (v4i){0, 0, 0, 0};

    const long* w64a = (const long*)(wt + (size_t)(cobase + ln15) * 576);
    const long* w64b = (const long*)(wt + (size_t)(cobase + 16 + ln15) * 576);

    #pragma unroll
    for (int kc = 0; kc < 18; ++kc) {
        const int khkw = kc >> 1;
        const int kh   = khkw / 3;
        const int kw   = khkw % 3;
        const int half = kc & 1;
        long a0 = w64a[kc * 4 + quad];
        long a1 = w64b[kc * 4 + quad];
        const int rowb  = (kh + r) * 114;
        const int cioff = half * 32 + quad * 8;
        #pragma unroll
        for (int nt = 0; nt < 7; ++nt) {
            int col = nt * 16 + ln15 + kw;   // = w + kw - 1, shifted by +1 pad
            long bfrag = *(const long*)&xs[(rowb + col) * 72 + cioff];
            acc[0][nt] = __builtin_amdgcn_mfma_i32_16x16x32_i8(a0, bfrag, acc[0][nt], 0, 0, 0);
            acc[1][nt] = __builtin_amdgcn_mfma_i32_16x16x32_i8(a1, bfrag, acc[1][nt], 0, 0, 0);
        }
    }

    // ---- epilogue: LDS transpose -> coalesced float4 stores ----
    // Phase mt: 2 h-rows x 32 co x 112 wp fp32, LDS pitch 116 dwords
    // (quad stride 464 dw mod 32 = 16 -> only free 2-way aliasing).
    const float s = ascale[0] * wscale[0];
    float* buf = (float*)xs;                 // 64*116*4 = 29,696 B <= 32,832
    float* outB = out + (size_t)b * COUT_ * HH * WW;

    #pragma unroll
    for (int mt = 0; mt < 2; ++mt) {
        __syncthreads();   // xs int8 reads done (mt=0) / prev phase read done (mt=1)
        #pragma unroll
        for (int reg = 0; reg < 4; ++reg) {
            int coL = coh * 16 + quad * 4 + reg;         // C/D: row = quad*4+reg
            float* dst = buf + (r * 32 + coL) * 116;
            #pragma unroll
            for (int nt = 0; nt < 7; ++nt)
                dst[nt * 16 + ln15] = (float)acc[mt][nt][reg] * s;   // C/D: col = lane&15
        }
        __syncthreads();
        // 1792 16B chunks: idx -> (rr, coL, wp4); lane-contiguous 448B runs
        #pragma unroll
        for (int i = 0; i < 7; ++i) {
            int idx = i * 256 + tid;
            int wp4 = idx % 28;
            int coL = (idx / 28) % 32;
            int rr  = idx / 896;
            float4 v = *(float4*)(buf + (rr * 32 + coL) * 116 + wp4 * 4);
            int co = (coL >> 4) * 32 + mt * 16 + (coL & 15);
            float bv = bias[co];
            v.x += bv; v.y += bv; v.z += bv; v.w += bv;
            *(float4*)(outB + ((size_t)co * HH + h0 + rr) * WW + wp4 * 4) = v;
        }
    }
}

extern "C" void kernel_launch(void* const* d_in, const int* in_sizes, int n_in,
                              void* d_out, int out_size, void* d_ws, size_t ws_size,
                              hipStream_t stream) {
    const int*    xq     = (const int*)d_in[0];
    const int*    wq     = (const int*)d_in[1];
    const float*  wscale = (const float*)d_in[2];
    const float*  ascale = (const float*)d_in[3];
    const float*  bias   = (const float*)d_in[4];
    int8_t* wt  = (int8_t*)d_ws;          // needs 36,864 B of scratch
    float*  out = (float*)d_out;

    wtrans_kernel<<<144, 256, 0, stream>>>(wq, wt);
    conv_kernel<<<BATCH * 56, 256, 0, stream>>>(xq, wt, wscale, ascale, bias, out);
}

// Round 5
// 217.510 us; speedup vs baseline: 1.2765x; 1.0120x over previous
//
#include <hip/hip_runtime.h>
#include <stdint.h>

#define BATCH 32
#define CIN   64
#define HH    112
#define WW    112
#define COUT_ 64

typedef int v4i __attribute__((ext_vector_type(4)));

// Kernel 0: weights int32 -> int8, [co][ci][kh][kw] -> [co][kh][kw][ci] so
// A-fragments (16 consecutive k = contiguous ci at a fixed tap) are 8B loads.
__global__ void wtrans_kernel(const int* __restrict__ wq, int8_t* __restrict__ wt) {
    int idx = blockIdx.x * 256 + threadIdx.x;   // 0 .. 36863, exact
    int ci   = idx & 63;
    int khkw = (idx >> 6) % 9;
    int co   = idx / 576;
    wt[idx] = (int8_t)wq[co * 576 + ci * 9 + khkw];
}

// Main conv kernel. Block = 256 threads (4 waves), one (b, 2-row) tile.
// R4 structure unchanged except occupancy: 4 blocks/CU (was 2) to overlap
// the memory-only staging phase of some blocks with the compute-only MFMA
// phase of others (phase-mixing latency hiding).
__launch_bounds__(256, 4)
__global__ void conv_kernel(const int* __restrict__ x,       // int32-materialized int8
                            const int8_t* __restrict__ wt,
                            const float*  __restrict__ wscale,
                            const float*  __restrict__ ascale,
                            const float*  __restrict__ bias,
                            float*        __restrict__ out) {
    __shared__ __align__(16) int8_t xs[4 * 114 * 72];   // 32,832 B; reused as fp32 buf

    const int tid = threadIdx.x;
    const int bt  = blockIdx.x;
    const int b   = bt / 56;
    const int h0  = (bt % 56) * 2;

    // ---- stage x tile: int32 -> int8, transpose w<->ci via v_perm ----
    #pragma unroll
    for (int it = 0; it < 7; ++it) {
        int job = tid + it * 256;
        int ci4 = job & 15;            // ci = ci4*4
        int cg  = (job >> 4) % 28;     // w = cg*4
        int row = job / 448;           // 0..3
        int hh  = h0 - 1 + row;
        v4i q0 = {0,0,0,0}, q1 = {0,0,0,0}, q2 = {0,0,0,0}, q3 = {0,0,0,0};
        if (hh >= 0 && hh < HH) {
            const v4i* gp = (const v4i*)
                (x + ((size_t)(b * CIN + ci4 * 4) * HH + hh) * WW + cg * 4);
            q0 = gp[0];
            q1 = gp[3136];          // +1 ci plane (112*112/4 int4s)
            q2 = gp[2 * 3136];
            q3 = gp[3 * 3136];
        }
        #pragma unroll
        for (int j = 0; j < 4; ++j) {
            uint32_t lo01 = __builtin_amdgcn_perm((uint32_t)q1[j], (uint32_t)q0[j], 0x0C0C0400u);
            uint32_t lo23 = __builtin_amdgcn_perm((uint32_t)q3[j], (uint32_t)q2[j], 0x04000C0Cu);
            *(uint32_t*)&xs[(row * 114 + cg * 4 + 1 + j) * 72 + ci4 * 4] = lo01 | lo23;
        }
    }
    if (tid < 128) {   // zero pad columns (input cols -1 and 112)
        int ci4 = tid & 15;
        int col = ((tid >> 4) & 1) ? 113 : 0;
        int row = tid >> 5;
        *(uint32_t*)&xs[(row * 114 + col) * 72 + ci4 * 4] = 0u;
    }
    __syncthreads();

    // ---- MFMA main loop (verified layout) ----
    const int lane = tid & 63;
    const int wave = tid >> 6;
    const int ln15 = lane & 15;
    const int quad = lane >> 4;
    const int r    = wave >> 1;        // output row within tile (0/1)
    const int coh  = wave & 1;         // cout half
    const int cobase = coh * 32;

    v4i acc[2][7];
    #pragma unroll
    for (int mt = 0; mt < 2; ++mt)
        #pragma unroll
        for (int nt = 0; nt < 7; ++nt)
            acc[mt][nt] = (v4i){0, 0, 0, 0};

    const long* w64a = (const long*)(wt + (size_t)(cobase + ln15) * 576);
    const long* w64b = (const long*)(wt + (size_t)(cobase + 16 + ln15) * 576);

    #pragma unroll
    for (int kc = 0; kc < 18; ++kc) {
        const int khkw = kc >> 1;
        const int kh   = khkw / 3;
        const int kw   = khkw % 3;
        const int half = kc & 1;
        long a0 = w64a[kc * 4 + quad];
        long a1 = w64b[kc * 4 + quad];
        const int rowb  = (kh + r) * 114;
        const int cioff = half * 32 + quad * 8;
        #pragma unroll
        for (int nt = 0; nt < 7; ++nt) {
            int col = nt * 16 + ln15 + kw;   // = w + kw - 1, shifted by +1 pad
            long bfrag = *(const long*)&xs[(rowb + col) * 72 + cioff];
            acc[0][nt] = __builtin_amdgcn_mfma_i32_16x16x32_i8(a0, bfrag, acc[0][nt], 0, 0, 0);
            acc[1][nt] = __builtin_amdgcn_mfma_i32_16x16x32_i8(a1, bfrag, acc[1][nt], 0, 0, 0);
        }
    }

    // ---- epilogue: LDS transpose -> coalesced float4 stores ----
    // Phase mt: 2 h-rows x 32 co x 112 wp fp32, LDS pitch 116 dwords
    // (quad stride 464 dw mod 32 = 16 -> only free 2-way aliasing).
    const float s = ascale[0] * wscale[0];
    float* buf = (float*)xs;                 // 64*116*4 = 29,696 B <= 32,832
    float* outB = out + (size_t)b * COUT_ * HH * WW;

    #pragma unroll
    for (int mt = 0; mt < 2; ++mt) {
        __syncthreads();   // xs int8 reads done (mt=0) / prev phase read done (mt=1)
        #pragma unroll
        for (int reg = 0; reg < 4; ++reg) {
            int coL = coh * 16 + quad * 4 + reg;         // C/D: row = quad*4+reg
            float* dst = buf + (r * 32 + coL) * 116;
            #pragma unroll
            for (int nt = 0; nt < 7; ++nt)
                dst[nt * 16 + ln15] = (float)acc[mt][nt][reg] * s;   // C/D: col = lane&15
        }
        __syncthreads();
        // 1792 16B chunks: idx -> (rr, coL, wp4); lane-contiguous 448B runs
        #pragma unroll
        for (int i = 0; i < 7; ++i) {
            int idx = i * 256 + tid;
            int wp4 = idx % 28;
            int coL = (idx / 28) % 32;
            int rr  = idx / 896;
            float4 v = *(float4*)(buf + (rr * 32 + coL) * 116 + wp4 * 4);
            int co = (coL >> 4) * 32 + mt * 16 + (coL & 15);
            float bv = bias[co];
            v.x += bv; v.y += bv; v.z += bv; v.w += bv;
            *(float4*)(outB + ((size_t)co * HH + h0 + rr) * WW + wp4 * 4) = v;
        }
    }
}

extern "C" void kernel_launch(void* const* d_in, const int* in_sizes, int n_in,
                              void* d_out, int out_size, void* d_ws, size_t ws_size,
                              hipStream_t stream) {
    const int*    xq     = (const int*)d_in[0];
    const int*    wq     = (const int*)d_in[1];
    const float*  wscale = (const float*)d_in[2];
    const float*  ascale = (const float*)d_in[3];
    const float*  bias   = (const float*)d_in[4];
    int8_t* wt  = (int8_t*)d_ws;          // needs 36,864 B of scratch
    float*  out = (float*)d_out;

    wtrans_kernel<<<144, 256, 0, stream>>>(wq, wt);
    conv_kernel<<<BATCH * 56, 256, 0, stream>>>(xq, wt, wscale, ascale, bias, out);
}